// Round 17
// baseline (220.430 us; speedup 1.0000x reference)
//
#include <hip/hip_runtime.h>
#include <hip/hip_bf16.h>
#include <stdint.h>

typedef __bf16 bf16x8 __attribute__((ext_vector_type(8)));
typedef float  f32x4  __attribute__((ext_vector_type(4)));
typedef unsigned short ushort8v __attribute__((ext_vector_type(8)));

__device__ __forceinline__ unsigned short f2bf(float f) {
  unsigned int u = __float_as_uint(f);
  u += 0x7FFF + ((u >> 16) & 1);          // round-to-nearest-even
  return (unsigned short)(u >> 16);
}
__device__ __forceinline__ float bf2f(unsigned short h) {
  return __uint_as_float(((unsigned int)h) << 16);
}

#define GLOAD_LDS(gptr, ldsptr)                                                     \
  __builtin_amdgcn_global_load_lds(                                                 \
      (const __attribute__((address_space(1))) unsigned int*)(gptr),                \
      (__attribute__((address_space(3))) unsigned int*)(ldsptr), 16, 0, 0)

// =============== 8-phase 256x256 GEMM (single-round grids: proj-qk, proj-v, S) ===============
// R12 schedule: staging to buf c^1 only, 1 half-tile lookahead, counted vmcnt(4),
// lgkmcnt(0)+sched_barrier after each barrier (rule 18).
// mode 0: C bf16 [M,N]*scale; mode 1: C bf16 vhT per-batch (b=row>>11, l=row&2047).
// tilemap 0: m204 XCD swizzle; tilemap 1: triangular (nt<=mt).
__global__ __launch_bounds__(512, 1) void gemm8p(
    const unsigned short* __restrict__ A,
    const unsigned short* __restrict__ B,
    void* __restrict__ C,
    int M, int N, int K, int ntn,
    long sAz, long sBz, long sCz,
    int mode, int tilemap, float scale)
{
  int mt, nt;
  const int orig = blockIdx.x;
  if (tilemap == 0) {
    const int nwg = gridDim.x;
    const int qq = nwg >> 3, rr = nwg & 7, xcd = orig & 7, oo = orig >> 3;
    const int wg = (xcd < rr ? xcd * (qq + 1) : rr * (qq + 1) + (xcd - rr) * qq) + oo;
    mt = wg / ntn; nt = wg % ntn;
  } else {
    mt = (int)((sqrtf(8.f * orig + 1.f) - 1.f) * 0.5f);
    int base = mt * (mt + 1) / 2;
    if (orig < base) { mt--; base = mt * (mt + 1) / 2; }
    else if (orig >= base + mt + 1) { mt++; base = mt * (mt + 1) / 2; }
    nt = orig - base;
  }
  const int z = blockIdx.y;
  A += sAz * (long)z;
  B += sBz * (long)z;

  __shared__ __align__(16) unsigned short lds[65536];   // 128 KB

  const int tid  = threadIdx.x;
  const int wave = tid >> 6;
  const int lane = tid & 63;
  const int wr = wave >> 2, wc = wave & 3;
  const int li = lane & 15;
  const int rslot = (((lane >> 4) ^ ((lane >> 1) & 3)) << 4);

  f32x4 acc[8][4];
#pragma unroll
  for (int i = 0; i < 8; ++i)
#pragma unroll
    for (int j = 0; j < 4; ++j) acc[i][j] = (f32x4){0.f, 0.f, 0.f, 0.f};

  const int nkt = K / 64;

  const int srow = tid >> 2;
  const long scol = (long)(((tid & 3) ^ ((tid >> 3) & 3)) << 3);
  const long aoff0 = (long)(mt * 256 + srow) * K + scol;
  const long aoff1 = (long)(mt * 256 + 128 + srow) * K + scol;
  const long boff0 = (long)(nt * 256 + srow) * K + scol;
  const long boff1 = (long)(nt * 256 + 128 + srow) * K + scol;
  const int stw = wave * 1024;

#define AB(c, kh) (((c) * 2 + (kh)) * 16384)
#define BB(c, kh) (65536 + ((c) * 2 + (kh)) * 16384)
#define STAGE_A(c, kh, jt) do { const long o_ = (long)(jt) * 64 + (kh) * 32;        \
    GLOAD_LDS(A + aoff0 + o_, (char*)lds + AB(c, kh) + stw);                        \
    GLOAD_LDS(A + aoff1 + o_, (char*)lds + AB(c, kh) + 8192 + stw); } while (0)
#define STAGE_B(c, kh, jt) do { const long o_ = (long)(jt) * 64 + (kh) * 32;        \
    GLOAD_LDS(B + boff0 + o_, (char*)lds + BB(c, kh) + stw);                        \
    GLOAD_LDS(B + boff1 + o_, (char*)lds + BB(c, kh) + 8192 + stw); } while (0)
#define RD_A(c, kk, ms, mf) \
  (*(const bf16x8*)((const char*)lds + AB(c, kk) + (wr * 128 + (ms) * 64 + (mf) * 16 + li) * 64 + rslot))
#define RD_B(c, kk, nf) \
  (*(const bf16x8*)((const char*)lds + BB(c, kk) + (wc * 64 + (nf) * 16 + li) * 64 + rslot))
#define MM(msb, bb) do {                                                            \
    _Pragma("unroll")                                                               \
    for (int mf_ = 0; mf_ < 4; ++mf_)                                               \
    _Pragma("unroll")                                                               \
      for (int nf_ = 0; nf_ < 4; ++nf_)                                             \
        acc[(msb) + mf_][nf_] = __builtin_amdgcn_mfma_f32_16x16x32_bf16(            \
            a[mf_], bb[nf_], acc[(msb) + mf_][nf_], 0, 0, 0); } while (0)
#define LGKM0_FENCE do {                                                            \
    asm volatile("s_waitcnt lgkmcnt(0)" ::: "memory");                              \
    __builtin_amdgcn_sched_barrier(0); } while (0)
#define BARRIER do { __builtin_amdgcn_s_barrier();                                  \
    asm volatile("" ::: "memory"); } while (0)

  STAGE_A(0, 0, 0); STAGE_B(0, 0, 0); STAGE_A(0, 1, 0); STAGE_B(0, 1, 0);
  asm volatile("s_waitcnt vmcnt(0)" ::: "memory");
  BARRIER;

  bf16x8 a[4], b0[4], b1[4];
  for (int j = 0; j < nkt; ++j) {
    const int c = j & 1;
    const bool s1 = (j + 1 < nkt);

#pragma unroll
    for (int nf = 0; nf < 4; ++nf) b0[nf] = RD_B(c, 0, nf);
#pragma unroll
    for (int mf = 0; mf < 4; ++mf) a[mf] = RD_A(c, 0, 0, mf);
    if (s1) STAGE_A(c ^ 1, 0, j + 1);
    BARRIER;
    LGKM0_FENCE;
    __builtin_amdgcn_s_setprio(1);
    MM(0, b0);
    __builtin_amdgcn_s_setprio(0);
    BARRIER;

#pragma unroll
    for (int mf = 0; mf < 4; ++mf) a[mf] = RD_A(c, 0, 1, mf);
    if (s1) STAGE_B(c ^ 1, 0, j + 1);
    BARRIER;
    LGKM0_FENCE;
    __builtin_amdgcn_s_setprio(1);
    MM(4, b0);
    __builtin_amdgcn_s_setprio(0);
    if (s1) { asm volatile("s_waitcnt vmcnt(4)" ::: "memory"); }
    else    { asm volatile("s_waitcnt vmcnt(0)" ::: "memory"); }
    BARRIER;

#pragma unroll
    for (int nf = 0; nf < 4; ++nf) b1[nf] = RD_B(c, 1, nf);
#pragma unroll
    for (int mf = 0; mf < 4; ++mf) a[mf] = RD_A(c, 1, 0, mf);
    if (s1) STAGE_A(c ^ 1, 1, j + 1);
    BARRIER;
    LGKM0_FENCE;
    __builtin_amdgcn_s_setprio(1);
    MM(0, b1);
    __builtin_amdgcn_s_setprio(0);
    BARRIER;

#pragma unroll
    for (int mf = 0; mf < 4; ++mf) a[mf] = RD_A(c, 1, 1, mf);
    if (s1) STAGE_B(c ^ 1, 1, j + 1);
    BARRIER;
    LGKM0_FENCE;
    __builtin_amdgcn_s_setprio(1);
    MM(4, b1);
    __builtin_amdgcn_s_setprio(0);
    if (s1) { asm volatile("s_waitcnt vmcnt(4)" ::: "memory"); }
    BARRIER;
  }
#undef AB
#undef BB
#undef STAGE_A
#undef STAGE_B
#undef RD_A
#undef RD_B
#undef MM
#undef LGKM0_FENCE
#undef BARRIER

  const int rb = mt * 256 + wr * 128;
  const int cb = nt * 256 + wc * 64;
  unsigned short* Cb = (unsigned short*)C + sCz * (long)z;
  if (mode == 0) {
#pragma unroll
    for (int mi = 0; mi < 8; ++mi)
#pragma unroll
      for (int ni = 0; ni < 4; ++ni) {
        const int row0 = rb + mi * 16 + ((lane >> 4) << 2);
        const int col  = cb + ni * 16 + (lane & 15);
#pragma unroll
        for (int jj = 0; jj < 4; ++jj)
          Cb[(long)(row0 + jj) * N + col] = f2bf(acc[mi][ni][jj] * scale);
      }
  } else {
    // vhT per-batch transposed epilogue (formula identical to proven gemm_bt mode 1)
#pragma unroll
    for (int mi = 0; mi < 8; ++mi)
#pragma unroll
      for (int ni = 0; ni < 4; ++ni) {
        const int row0 = rb + mi * 16 + ((lane >> 4) << 2);
        const int col  = cb + ni * 16 + (lane & 15);
#pragma unroll
        for (int jj = 0; jj < 4; ++jj) {
          const int row = row0 + jj;
          const int b = row >> 11, l = row & 2047;
          Cb[((long)b * N + col) * 2048 + l] = f2bf(acc[mi][ni][jj]);
        }
      }
  }
}

#define BM 128
#define BN 128
#define BK 32

// ============ 128x128 3-buf GEMM (PV / out-proj) ============
// mode 0: C bf16 [M,N]*scale; mode 2: C fp32 [M,N]*scale
// tilemap 0: m204 XCD chunk swizzle; 2: paired causal map + K-limit (PV)
__global__ __launch_bounds__(256, 3) void gemm_bt(
    const unsigned short* __restrict__ A,
    const unsigned short* __restrict__ B,
    void* __restrict__ C,
    int M, int N, int K, int ntiles,
    long sAz, long sBz, long sCz,
    int mode, int tilemap, float scale)
{
  int mt, nt;
  const int orig = blockIdx.x;
  if (tilemap == 0) {
    const int nwg = gridDim.x;
    const int qq = nwg >> 3, rr = nwg & 7, xc = orig & 7, oo = orig >> 3;
    const int wg = (xc < rr ? xc * (qq + 1) : rr * (qq + 1) + (xc - rr) * qq) + oo;
    mt = wg / ntiles; nt = wg % ntiles;
  } else {
    const int c = orig & 15;
    mt = (c & 8) ? (15 - (c & 7)) : c;
    nt = orig >> 4;
  }
  const int z = blockIdx.y;

  A += sAz * (long)z;
  B += sBz * (long)z;

  __shared__ __align__(16) unsigned short As[3][BM * BK];
  __shared__ __align__(16) unsigned short Bs[3][BN * BK];

  const int tid  = threadIdx.x;
  const int wave = tid >> 6;
  const int lane = tid & 63;
  const int wr = wave >> 1, wc = wave & 1;

  f32x4 acc[4][4];
#pragma unroll
  for (int i = 0; i < 4; ++i)
#pragma unroll
    for (int j = 0; j < 4; ++j) acc[i][j] = (f32x4){0.f, 0.f, 0.f, 0.f};

  int kiters = K / BK;
  if (tilemap == 2) { const int kl = (mt + 1) * (BM / BK); if (kl < kiters) kiters = kl; }

  const int r0 = tid >> 2, s0 = tid & 3;
  const int c0 = ((s0 ^ ((r0 >> 1) & 3)) << 3);
  const int r1 = r0 + 64;
  const int c1 = ((s0 ^ ((r1 >> 1) & 3)) << 3);
  const long aoff0 = (long)(mt * BM + r0) * K + c0;
  const long aoff1 = (long)(mt * BM + r1) * K + c1;
  const long boff0 = (long)(nt * BN + r0) * K + c0;
  const long boff1 = (long)(nt * BN + r1) * K + c1;
  const unsigned ldsw = wave * 1024;

#define STAGE(bi, k0)                                                     \
  do {                                                                    \
    GLOAD_LDS(A + aoff0 + (k0), (char*)&As[bi][0]    + ldsw);             \
    GLOAD_LDS(A + aoff1 + (k0), (char*)&As[bi][2048] + ldsw);             \
    GLOAD_LDS(B + boff0 + (k0), (char*)&Bs[bi][0]    + ldsw);             \
    GLOAD_LDS(B + boff1 + (k0), (char*)&Bs[bi][2048] + ldsw);             \
  } while (0)

  STAGE(0, 0);
  if (kiters > 1) STAGE(1, BK);

  int cur = 0;
  for (int kt = 0; kt < kiters; ++kt) {
    const int rem = kiters - 1 - kt;
    if (rem >= 2) {
      int sb = cur + 2; if (sb >= 3) sb -= 3;
      STAGE(sb, (kt + 2) * BK);
      asm volatile("s_waitcnt vmcnt(8)" ::: "memory");
    } else if (rem == 1) {
      asm volatile("s_waitcnt vmcnt(4)" ::: "memory");
    } else {
      asm volatile("s_waitcnt vmcnt(0)" ::: "memory");
    }
    __builtin_amdgcn_s_barrier();
    asm volatile("" ::: "memory");

    bf16x8 af[4], bfr[4];
#pragma unroll
    for (int i = 0; i < 4; ++i) {
      const int ar = wr * 64 + i * 16 + (lane & 15);
      const int as = ((lane >> 4) ^ ((ar >> 1) & 3)) << 3;
      af[i] = *(const bf16x8*)&As[cur][ar * BK + as];
      const int br = wc * 64 + i * 16 + (lane & 15);
      const int bs = ((lane >> 4) ^ ((br >> 1) & 3)) << 3;
      bfr[i] = *(const bf16x8*)&Bs[cur][br * BK + bs];
    }
#pragma unroll
    for (int mi = 0; mi < 4; ++mi)
#pragma unroll
      for (int ni = 0; ni < 4; ++ni)
        acc[mi][ni] = __builtin_amdgcn_mfma_f32_16x16x32_bf16(af[mi], bfr[ni], acc[mi][ni], 0, 0, 0);

    asm volatile("" ::: "memory");
    __builtin_amdgcn_s_barrier();
    cur = (cur == 2) ? 0 : cur + 1;
  }
#undef STAGE

  const int rb = mt * BM + wr * 64;
  const int cb = nt * BN + wc * 64;

  if (mode == 0) {
    unsigned short* Cb = (unsigned short*)C + sCz * (long)z;
#pragma unroll
    for (int mi = 0; mi < 4; ++mi)
#pragma unroll
      for (int ni = 0; ni < 4; ++ni) {
        const int row0 = rb + mi * 16 + ((lane >> 4) << 2);
        const int col  = cb + ni * 16 + (lane & 15);
#pragma unroll
        for (int j = 0; j < 4; ++j)
          Cb[(long)(row0 + j) * N + col] = f2bf(acc[mi][ni][j] * scale);
      }
  } else {
    float* Cf = (float*)C + sCz * (long)z;
#pragma unroll
    for (int mi = 0; mi < 4; ++mi)
#pragma unroll
      for (int ni = 0; ni < 4; ++ni) {
        const int row0 = rb + mi * 16 + ((lane >> 4) << 2);
        const int col  = cb + ni * 16 + (lane & 15);
#pragma unroll
        for (int j = 0; j < 4; ++j)
          Cf[(long)(row0 + j) * N + col] = acc[mi][ni][j] * scale;
      }
  }
}

// work-balanced paired causal softmax: block handles rows q and 2047-q of one batch.
__global__ __launch_bounds__(256) void softmax_causal(
    const unsigned short* __restrict__ S, unsigned short* __restrict__ P)
{
  const int pid = blockIdx.x;            // 0..4095
  const int b = pid >> 10;
  const int qa = pid & 1023;
  const int tid = threadIdx.x, lane = tid & 63, wave = tid >> 6;
  const int base = tid * 8;
  __shared__ float red[8];

#pragma unroll
  for (int half = 0; half < 2; ++half) {
    const int q = half ? (2047 - qa) : qa;
    const unsigned short* srow = S + ((long)b * 2048 + q) * 2048;
    unsigned short* prow = P + ((long)b * 2048 + q) * 2048;
    const int len = q + 1;
    const int lenceil = ((q >> 7) + 1) << 7;
    const bool active = base < lenceil;

    float vv[8];
#pragma unroll
    for (int i = 0; i < 8; ++i) vv[i] = -3.4e38f;
    if (active) {
      ushort8v xv = *(const ushort8v*)(srow + base);
#pragma unroll
      for (int i = 0; i < 8; ++i) vv[i] = bf2f(xv[i]);
    }

    float m = -3.4e38f;
#pragma unroll
    for (int i = 0; i < 8; ++i) if (base + i < len) m = fmaxf(m, vv[i]);
#pragma unroll
    for (int o = 32; o; o >>= 1) m = fmaxf(m, __shfl_xor(m, o));
    if (lane == 0) red[wave] = m;
    __syncthreads();
    m = fmaxf(fmaxf(red[0], red[1]), fmaxf(red[2], red[3]));

    float p[8], s = 0.f;
#pragma unroll
    for (int i = 0; i < 8; ++i) {
      p[i] = (base + i < len) ? __expf(vv[i] - m) : 0.f;
      s += p[i];
    }
#pragma unroll
    for (int o = 32; o; o >>= 1) s += __shfl_xor(s, o);
    if (lane == 0) red[4 + wave] = s;
    __syncthreads();
    s = (red[4] + red[5]) + (red[6] + red[7]);
    const float inv = 1.f / s;

    if (active) {
      ushort8v o16;
#pragma unroll
      for (int i = 0; i < 8; ++i) o16[i] = f2bf(p[i] * inv);
      *(ushort8v*)(prow + base) = o16;
    }
    __syncthreads();
  }
}

// merged fp32 -> bf16 (RNE): q,k,v + 4 weights
__global__ __launch_bounds__(256) void convert_all(
    const float* __restrict__ q, const float* __restrict__ k, const float* __restrict__ v,
    const float* __restrict__ wq, const float* __restrict__ wk,
    const float* __restrict__ wv, const float* __restrict__ wp,
    unsigned short* __restrict__ qkv, unsigned short* __restrict__ wb)
{
  const long NQ = 8192L * 1024 / 4;
  const long NW = 1024L * 1024 / 4;
  const int blk = blockIdx.x;
  const float* src; unsigned short* dst; long n; int nb, bb;
  if (blk < 1536) {
    const int s = blk >> 9;
    src = (s == 0) ? q : (s == 1) ? k : v;
    dst = qkv + (long)s * (8192L * 1024);
    n = NQ; nb = 512; bb = blk & 511;
  } else {
    const int s = (blk - 1536) >> 6;
    src = (s == 0) ? wq : (s == 1) ? wk : (s == 2) ? wv : wp;
    dst = wb + (long)s * (1024L * 1024);
    n = NW; nb = 64; bb = (blk - 1536) & 63;
  }
  for (long i = (long)bb * 256 + threadIdx.x; i < n; i += (long)nb * 256) {
    float4 x = ((const float4*)src)[i];
    ushort4 o;
    o.x = f2bf(x.x); o.y = f2bf(x.y); o.z = f2bf(x.z); o.w = f2bf(x.w);
    ((ushort4*)dst)[i] = o;
  }
}

extern "C" void kernel_launch(void* const* d_in, const int* in_sizes, int n_in,
                              void* d_out, int out_size, void* d_ws, size_t ws_size,
                              hipStream_t stream) {
  const float* q  = (const float*)d_in[0];
  const float* k  = (const float*)d_in[1];
  const float* v  = (const float*)d_in[2];
  const float* Wq = (const float*)d_in[3];
  const float* Wk = (const float*)d_in[4];
  const float* Wv = (const float*)d_in[5];
  const float* Wp = (const float*)d_in[6];
  float* out = (float*)d_out;

  const long D  = 1024;
  const long L  = 2048;
  const long ND = 8192 * D;
  const long NS = 4L * L * L;

  char* ws = (char*)d_ws;
  unsigned short* qh    = (unsigned short*)ws;         // 16 MB (z=0)
  unsigned short* kh    = qh  + ND;                    // 16 MB (z=1)
  unsigned short* vhT   = kh  + ND;                    // 16 MB (transposed)
  unsigned short* wbf   = vhT + ND;                    // 8 MB (4 weights)
  unsigned short* S     = wbf + 4L * D * D;            // 32 MB (bf16)
  unsigned short* qkvbf = S   + NS;                    // 48 MB (dead after proj)
  unsigned short* P     = qkvbf;                       // 32 MB, aliases dead qkv
  unsigned short* ybf   = P + NS;                      // 16 MB, aliases dead qkv

  // 1) convert inputs + weights to bf16
  convert_all<<<1792, 256, 0, stream>>>(q, k, v, Wq, Wk, Wv, Wp, qkvbf, wbf);

  // 2a) projections qh, kh: 8-phase 256^2, 256 blocks = exactly 1 round
  gemm8p<<<dim3(128, 2), 512, 0, stream>>>(qkvbf, wbf, qh,
      8192, 1024, 1024, 4, ND, D * D, ND, 0, 0, 1.0f);

  // 2b) projection vhT: 8-phase 256^2, 128 blocks, transposed epilogue
  gemm8p<<<dim3(128, 1), 512, 0, stream>>>(qkvbf + 2 * ND, wbf + 2 * D * D, vhT,
      8192, 1024, 1024, 4, 0, 0, 0, 1, 0, 1.0f);

  // 3) S = qh * kh^T * 0.125 (bf16 out), 8-phase 256^2, triangular 36 tiles/z
  gemm8p<<<dim3(36, 4), 512, 0, stream>>>(qh, kh, S,
      2048, 2048, 1024, 8, L * D, L * D, L * L, 0, 1, 0.125f);

  // 4) causal softmax (bf16 in/out, paired rows q & 2047-q)
  softmax_causal<<<4096, 256, 0, stream>>>(S, P);

  // 5) Y = P * vh (paired XCD map + K-limit)
  gemm_bt<<<dim3(128, 4), 256, 0, stream>>>(P, vhT, ybf,
      2048, 1024, 2048, 8, L * L, D * L, L * D, 0, 2, 1.0f);

  // 6) out = Y * Wproj^T (fp32, 2-phase 128^2, 512 blocks)
  gemm_bt<<<dim3(512, 1), 256, 0, stream>>>(ybf, wbf + 3 * D * D, out,
      8192, 1024, 1024, 8, 0, 0, 0, 2, 0, 1.0f);
}

// Round 18
// 212.699 us; speedup vs baseline: 1.0363x; 1.0363x over previous
//
#include <hip/hip_runtime.h>
#include <hip/hip_bf16.h>
#include <stdint.h>

typedef __bf16 bf16x8 __attribute__((ext_vector_type(8)));
typedef float  f32x4  __attribute__((ext_vector_type(4)));
typedef unsigned short ushort8v __attribute__((ext_vector_type(8)));

__device__ __forceinline__ unsigned short f2bf(float f) {
  unsigned int u = __float_as_uint(f);
  u += 0x7FFF + ((u >> 16) & 1);          // round-to-nearest-even
  return (unsigned short)(u >> 16);
}
__device__ __forceinline__ float bf2f(unsigned short h) {
  return __uint_as_float(((unsigned int)h) << 16);
}

#define GLOAD_LDS(gptr, ldsptr)                                                     \
  __builtin_amdgcn_global_load_lds(                                                 \
      (const __attribute__((address_space(1))) unsigned int*)(gptr),                \
      (__attribute__((address_space(3))) unsigned int*)(ldsptr), 16, 0, 0)

// =============== 8-phase 256x256 GEMM (S-GEMM only: 144-block single round) ===============
// R12 schedule: staging to buf c^1 only, 1 half-tile lookahead, counted vmcnt(4),
// lgkmcnt(0)+sched_barrier after each barrier (rule 18). tilemap 1: triangular (nt<=mt).
__global__ __launch_bounds__(512, 1) void gemm8p(
    const unsigned short* __restrict__ A,
    const unsigned short* __restrict__ B,
    void* __restrict__ C,
    int M, int N, int K, int ntn,
    long sAz, long sBz, long sCz,
    int mode, int tilemap, float scale)
{
  int mt, nt;
  const int orig = blockIdx.x;
  if (tilemap == 0) {
    const int nwg = gridDim.x;
    const int qq = nwg >> 3, rr = nwg & 7, xcd = orig & 7, oo = orig >> 3;
    const int wg = (xcd < rr ? xcd * (qq + 1) : rr * (qq + 1) + (xcd - rr) * qq) + oo;
    mt = wg / ntn; nt = wg % ntn;
  } else {
    mt = (int)((sqrtf(8.f * orig + 1.f) - 1.f) * 0.5f);
    int base = mt * (mt + 1) / 2;
    if (orig < base) { mt--; base = mt * (mt + 1) / 2; }
    else if (orig >= base + mt + 1) { mt++; base = mt * (mt + 1) / 2; }
    nt = orig - base;
  }
  const int z = blockIdx.y;
  A += sAz * (long)z;
  B += sBz * (long)z;

  __shared__ __align__(16) unsigned short lds[65536];   // 128 KB

  const int tid  = threadIdx.x;
  const int wave = tid >> 6;
  const int lane = tid & 63;
  const int wr = wave >> 2, wc = wave & 3;
  const int li = lane & 15;
  const int rslot = (((lane >> 4) ^ ((lane >> 1) & 3)) << 4);

  f32x4 acc[8][4];
#pragma unroll
  for (int i = 0; i < 8; ++i)
#pragma unroll
    for (int j = 0; j < 4; ++j) acc[i][j] = (f32x4){0.f, 0.f, 0.f, 0.f};

  const int nkt = K / 64;

  const int srow = tid >> 2;
  const long scol = (long)(((tid & 3) ^ ((tid >> 3) & 3)) << 3);
  const long aoff0 = (long)(mt * 256 + srow) * K + scol;
  const long aoff1 = (long)(mt * 256 + 128 + srow) * K + scol;
  const long boff0 = (long)(nt * 256 + srow) * K + scol;
  const long boff1 = (long)(nt * 256 + 128 + srow) * K + scol;
  const int stw = wave * 1024;

#define AB(c, kh) (((c) * 2 + (kh)) * 16384)
#define BB(c, kh) (65536 + ((c) * 2 + (kh)) * 16384)
#define STAGE_A(c, kh, jt) do { const long o_ = (long)(jt) * 64 + (kh) * 32;        \
    GLOAD_LDS(A + aoff0 + o_, (char*)lds + AB(c, kh) + stw);                        \
    GLOAD_LDS(A + aoff1 + o_, (char*)lds + AB(c, kh) + 8192 + stw); } while (0)
#define STAGE_B(c, kh, jt) do { const long o_ = (long)(jt) * 64 + (kh) * 32;        \
    GLOAD_LDS(B + boff0 + o_, (char*)lds + BB(c, kh) + stw);                        \
    GLOAD_LDS(B + boff1 + o_, (char*)lds + BB(c, kh) + 8192 + stw); } while (0)
#define RD_A(c, kk, ms, mf) \
  (*(const bf16x8*)((const char*)lds + AB(c, kk) + (wr * 128 + (ms) * 64 + (mf) * 16 + li) * 64 + rslot))
#define RD_B(c, kk, nf) \
  (*(const bf16x8*)((const char*)lds + BB(c, kk) + (wc * 64 + (nf) * 16 + li) * 64 + rslot))
#define MM(msb, bb) do {                                                            \
    _Pragma("unroll")                                                               \
    for (int mf_ = 0; mf_ < 4; ++mf_)                                               \
    _Pragma("unroll")                                                               \
      for (int nf_ = 0; nf_ < 4; ++nf_)                                             \
        acc[(msb) + mf_][nf_] = __builtin_amdgcn_mfma_f32_16x16x32_bf16(            \
            a[mf_], bb[nf_], acc[(msb) + mf_][nf_], 0, 0, 0); } while (0)
#define LGKM0_FENCE do {                                                            \
    asm volatile("s_waitcnt lgkmcnt(0)" ::: "memory");                              \
    __builtin_amdgcn_sched_barrier(0); } while (0)
#define BARRIER do { __builtin_amdgcn_s_barrier();                                  \
    asm volatile("" ::: "memory"); } while (0)

  STAGE_A(0, 0, 0); STAGE_B(0, 0, 0); STAGE_A(0, 1, 0); STAGE_B(0, 1, 0);
  asm volatile("s_waitcnt vmcnt(0)" ::: "memory");
  BARRIER;

  bf16x8 a[4], b0[4], b1[4];
  for (int j = 0; j < nkt; ++j) {
    const int c = j & 1;
    const bool s1 = (j + 1 < nkt);

#pragma unroll
    for (int nf = 0; nf < 4; ++nf) b0[nf] = RD_B(c, 0, nf);
#pragma unroll
    for (int mf = 0; mf < 4; ++mf) a[mf] = RD_A(c, 0, 0, mf);
    if (s1) STAGE_A(c ^ 1, 0, j + 1);
    BARRIER;
    LGKM0_FENCE;
    __builtin_amdgcn_s_setprio(1);
    MM(0, b0);
    __builtin_amdgcn_s_setprio(0);
    BARRIER;

#pragma unroll
    for (int mf = 0; mf < 4; ++mf) a[mf] = RD_A(c, 0, 1, mf);
    if (s1) STAGE_B(c ^ 1, 0, j + 1);
    BARRIER;
    LGKM0_FENCE;
    __builtin_amdgcn_s_setprio(1);
    MM(4, b0);
    __builtin_amdgcn_s_setprio(0);
    if (s1) { asm volatile("s_waitcnt vmcnt(4)" ::: "memory"); }
    else    { asm volatile("s_waitcnt vmcnt(0)" ::: "memory"); }
    BARRIER;

#pragma unroll
    for (int nf = 0; nf < 4; ++nf) b1[nf] = RD_B(c, 1, nf);
#pragma unroll
    for (int mf = 0; mf < 4; ++mf) a[mf] = RD_A(c, 1, 0, mf);
    if (s1) STAGE_A(c ^ 1, 1, j + 1);
    BARRIER;
    LGKM0_FENCE;
    __builtin_amdgcn_s_setprio(1);
    MM(0, b1);
    __builtin_amdgcn_s_setprio(0);
    BARRIER;

#pragma unroll
    for (int mf = 0; mf < 4; ++mf) a[mf] = RD_A(c, 1, 1, mf);
    if (s1) STAGE_B(c ^ 1, 1, j + 1);
    BARRIER;
    LGKM0_FENCE;
    __builtin_amdgcn_s_setprio(1);
    MM(4, b1);
    __builtin_amdgcn_s_setprio(0);
    if (s1) { asm volatile("s_waitcnt vmcnt(4)" ::: "memory"); }
    BARRIER;
  }
#undef AB
#undef BB
#undef STAGE_A
#undef STAGE_B
#undef RD_A
#undef RD_B
#undef MM
#undef LGKM0_FENCE
#undef BARRIER

  const int rb = mt * 256 + wr * 128;
  const int cb = nt * 256 + wc * 64;
  unsigned short* Cb = (unsigned short*)C + sCz * (long)z;
#pragma unroll
  for (int mi = 0; mi < 8; ++mi)
#pragma unroll
    for (int ni = 0; ni < 4; ++ni) {
      const int row0 = rb + mi * 16 + ((lane >> 4) << 2);
      const int col  = cb + ni * 16 + (lane & 15);
#pragma unroll
      for (int jj = 0; jj < 4; ++jj)
        Cb[(long)(row0 + jj) * N + col] = f2bf(acc[mi][ni][jj] * scale);
    }
}

#define BM 128
#define BN 128
#define BK 32

// ============ 128x128 3-buf GEMM (proj / PV / out-proj) ============
// mode 0: C bf16 [M,N]*scale; mode 2: C fp32 [M,N]*scale
// mode 3: merged projections (z<2 -> bf16 [M,N]; z==2 -> vhT per-batch)
// tilemap 0: m204 XCD chunk swizzle
// tilemap 2: paired causal map mt={c,15-c} + K-limit
// tilemap 3: flat PV map, 512 blocks: o&255 -> (mt desc, variant), o>>8 picks
//            co-resident twin with SAME mt -> long blocks stay 2-resident (tail fix)
__global__ __launch_bounds__(256, 3) void gemm_bt(
    const unsigned short* __restrict__ A,
    const unsigned short* __restrict__ B,
    void* __restrict__ C,
    int M, int N, int K, int ntiles,
    long sAz, long sBz, long sCz,
    int mode, int tilemap, float scale)
{
  int mt, nt;
  int z = blockIdx.y;
  const int orig = blockIdx.x;
  if (tilemap == 0) {
    const int nwg = gridDim.x;
    const int qq = nwg >> 3, rr = nwg & 7, xc = orig & 7, oo = orig >> 3;
    const int wg = (xc < rr ? xc * (qq + 1) : rr * (qq + 1) + (xc - rr) * qq) + oo;
    mt = wg / ntiles; nt = wg % ntiles;
  } else if (tilemap == 2) {
    const int c = orig & 15;
    mt = (c & 8) ? (15 - (c & 7)) : c;
    nt = orig >> 4;
  } else {
    // flat PV map: r=o&255, h=o>>8; blocks o and o+256 share mt (same CU under RR)
    const int r = orig & 255, h = orig >> 8;
    mt = 15 - (r >> 4);                    // LPT: longest first
    const int v = (r & 15) | (h << 4);     // 0..31
    nt = v & 7;
    z  = v >> 3;
  }
  const int emode = (mode == 3) ? (z == 2 ? 1 : 0) : mode;

  A += sAz * (long)z;
  B += sBz * (long)z;

  __shared__ __align__(16) unsigned short As[3][BM * BK];
  __shared__ __align__(16) unsigned short Bs[3][BN * BK];

  const int tid  = threadIdx.x;
  const int wave = tid >> 6;
  const int lane = tid & 63;
  const int wr = wave >> 1, wc = wave & 1;

  f32x4 acc[4][4];
#pragma unroll
  for (int i = 0; i < 4; ++i)
#pragma unroll
    for (int j = 0; j < 4; ++j) acc[i][j] = (f32x4){0.f, 0.f, 0.f, 0.f};

  int kiters = K / BK;
  if (tilemap >= 2) { const int kl = (mt + 1) * (BM / BK); if (kl < kiters) kiters = kl; }

  const int r0 = tid >> 2, s0 = tid & 3;
  const int c0 = ((s0 ^ ((r0 >> 1) & 3)) << 3);
  const int r1 = r0 + 64;
  const int c1 = ((s0 ^ ((r1 >> 1) & 3)) << 3);
  const long aoff0 = (long)(mt * BM + r0) * K + c0;
  const long aoff1 = (long)(mt * BM + r1) * K + c1;
  const long boff0 = (long)(nt * BN + r0) * K + c0;
  const long boff1 = (long)(nt * BN + r1) * K + c1;
  const unsigned ldsw = wave * 1024;

#define STAGE(bi, k0)                                                     \
  do {                                                                    \
    GLOAD_LDS(A + aoff0 + (k0), (char*)&As[bi][0]    + ldsw);             \
    GLOAD_LDS(A + aoff1 + (k0), (char*)&As[bi][2048] + ldsw);             \
    GLOAD_LDS(B + boff0 + (k0), (char*)&Bs[bi][0]    + ldsw);             \
    GLOAD_LDS(B + boff1 + (k0), (char*)&Bs[bi][2048] + ldsw);             \
  } while (0)

  STAGE(0, 0);
  if (kiters > 1) STAGE(1, BK);

  int cur = 0;
  for (int kt = 0; kt < kiters; ++kt) {
    const int rem = kiters - 1 - kt;
    if (rem >= 2) {
      int sb = cur + 2; if (sb >= 3) sb -= 3;
      STAGE(sb, (kt + 2) * BK);
      asm volatile("s_waitcnt vmcnt(8)" ::: "memory");
    } else if (rem == 1) {
      asm volatile("s_waitcnt vmcnt(4)" ::: "memory");
    } else {
      asm volatile("s_waitcnt vmcnt(0)" ::: "memory");
    }
    __builtin_amdgcn_s_barrier();
    asm volatile("" ::: "memory");

    bf16x8 af[4], bfr[4];
#pragma unroll
    for (int i = 0; i < 4; ++i) {
      const int ar = wr * 64 + i * 16 + (lane & 15);
      const int as = ((lane >> 4) ^ ((ar >> 1) & 3)) << 3;
      af[i] = *(const bf16x8*)&As[cur][ar * BK + as];
      const int br = wc * 64 + i * 16 + (lane & 15);
      const int bs = ((lane >> 4) ^ ((br >> 1) & 3)) << 3;
      bfr[i] = *(const bf16x8*)&Bs[cur][br * BK + bs];
    }
#pragma unroll
    for (int mi = 0; mi < 4; ++mi)
#pragma unroll
      for (int ni = 0; ni < 4; ++ni)
        acc[mi][ni] = __builtin_amdgcn_mfma_f32_16x16x32_bf16(af[mi], bfr[ni], acc[mi][ni], 0, 0, 0);

    asm volatile("" ::: "memory");
    __builtin_amdgcn_s_barrier();
    cur = (cur == 2) ? 0 : cur + 1;
  }
#undef STAGE

  const int rb = mt * BM + wr * 64;
  const int cb = nt * BN + wc * 64;

  if (emode == 0) {
    unsigned short* Cb = (unsigned short*)C + sCz * (long)z;
#pragma unroll
    for (int mi = 0; mi < 4; ++mi)
#pragma unroll
      for (int ni = 0; ni < 4; ++ni) {
        const int row0 = rb + mi * 16 + ((lane >> 4) << 2);
        const int col  = cb + ni * 16 + (lane & 15);
#pragma unroll
        for (int j = 0; j < 4; ++j)
          Cb[(long)(row0 + j) * N + col] = f2bf(acc[mi][ni][j] * scale);
      }
  } else if (emode == 1) {
    unsigned short* Cb = (unsigned short*)C + sCz * (long)z;
#pragma unroll
    for (int mi = 0; mi < 4; ++mi)
#pragma unroll
      for (int ni = 0; ni < 4; ++ni) {
        const int row0 = rb + mi * 16 + ((lane >> 4) << 2);
        const int col  = cb + ni * 16 + (lane & 15);
#pragma unroll
        for (int j = 0; j < 4; ++j) {
          const int row = row0 + j;
          const int b = row >> 11, l = row & 2047;
          Cb[((long)b * N + col) * 2048 + l] = f2bf(acc[mi][ni][j]);
        }
      }
  } else {
    float* Cf = (float*)C + sCz * (long)z;
#pragma unroll
    for (int mi = 0; mi < 4; ++mi)
#pragma unroll
      for (int ni = 0; ni < 4; ++ni) {
        const int row0 = rb + mi * 16 + ((lane >> 4) << 2);
        const int col  = cb + ni * 16 + (lane & 15);
#pragma unroll
        for (int j = 0; j < 4; ++j)
          Cf[(long)(row0 + j) * N + col] = acc[mi][ni][j] * scale;
      }
  }
}

// work-balanced paired causal softmax: block handles rows q and 2047-q of one batch.
__global__ __launch_bounds__(256) void softmax_causal(
    const unsigned short* __restrict__ S, unsigned short* __restrict__ P)
{
  const int pid = blockIdx.x;            // 0..4095
  const int b = pid >> 10;
  const int qa = pid & 1023;
  const int tid = threadIdx.x, lane = tid & 63, wave = tid >> 6;
  const int base = tid * 8;
  __shared__ float red[8];

#pragma unroll
  for (int half = 0; half < 2; ++half) {
    const int q = half ? (2047 - qa) : qa;
    const unsigned short* srow = S + ((long)b * 2048 + q) * 2048;
    unsigned short* prow = P + ((long)b * 2048 + q) * 2048;
    const int len = q + 1;
    const int lenceil = ((q >> 7) + 1) << 7;
    const bool active = base < lenceil;

    float vv[8];
#pragma unroll
    for (int i = 0; i < 8; ++i) vv[i] = -3.4e38f;
    if (active) {
      ushort8v xv = *(const ushort8v*)(srow + base);
#pragma unroll
      for (int i = 0; i < 8; ++i) vv[i] = bf2f(xv[i]);
    }

    float m = -3.4e38f;
#pragma unroll
    for (int i = 0; i < 8; ++i) if (base + i < len) m = fmaxf(m, vv[i]);
#pragma unroll
    for (int o = 32; o; o >>= 1) m = fmaxf(m, __shfl_xor(m, o));
    if (lane == 0) red[wave] = m;
    __syncthreads();
    m = fmaxf(fmaxf(red[0], red[1]), fmaxf(red[2], red[3]));

    float p[8], s = 0.f;
#pragma unroll
    for (int i = 0; i < 8; ++i) {
      p[i] = (base + i < len) ? __expf(vv[i] - m) : 0.f;
      s += p[i];
    }
#pragma unroll
    for (int o = 32; o; o >>= 1) s += __shfl_xor(s, o);
    if (lane == 0) red[4 + wave] = s;
    __syncthreads();
    s = (red[4] + red[5]) + (red[6] + red[7]);
    const float inv = 1.f / s;

    if (active) {
      ushort8v o16;
#pragma unroll
      for (int i = 0; i < 8; ++i) o16[i] = f2bf(p[i] * inv);
      *(ushort8v*)(prow + base) = o16;
    }
    __syncthreads();
  }
}

// merged fp32 -> bf16 (RNE): q,k,v + 4 weights
__global__ __launch_bounds__(256) void convert_all(
    const float* __restrict__ q, const float* __restrict__ k, const float* __restrict__ v,
    const float* __restrict__ wq, const float* __restrict__ wk,
    const float* __restrict__ wv, const float* __restrict__ wp,
    unsigned short* __restrict__ qkv, unsigned short* __restrict__ wb)
{
  const long NQ = 8192L * 1024 / 4;
  const long NW = 1024L * 1024 / 4;
  const int blk = blockIdx.x;
  const float* src; unsigned short* dst; long n; int nb, bb;
  if (blk < 1536) {
    const int s = blk >> 9;
    src = (s == 0) ? q : (s == 1) ? k : v;
    dst = qkv + (long)s * (8192L * 1024);
    n = NQ; nb = 512; bb = blk & 511;
  } else {
    const int s = (blk - 1536) >> 6;
    src = (s == 0) ? wq : (s == 1) ? wk : (s == 2) ? wv : wp;
    dst = wb + (long)s * (1024L * 1024);
    n = NW; nb = 64; bb = (blk - 1536) & 63;
  }
  for (long i = (long)bb * 256 + threadIdx.x; i < n; i += (long)nb * 256) {
    float4 x = ((const float4*)src)[i];
    ushort4 o;
    o.x = f2bf(x.x); o.y = f2bf(x.y); o.z = f2bf(x.z); o.w = f2bf(x.w);
    ((ushort4*)dst)[i] = o;
  }
}

extern "C" void kernel_launch(void* const* d_in, const int* in_sizes, int n_in,
                              void* d_out, int out_size, void* d_ws, size_t ws_size,
                              hipStream_t stream) {
  const float* q  = (const float*)d_in[0];
  const float* k  = (const float*)d_in[1];
  const float* v  = (const float*)d_in[2];
  const float* Wq = (const float*)d_in[3];
  const float* Wk = (const float*)d_in[4];
  const float* Wv = (const float*)d_in[5];
  const float* Wp = (const float*)d_in[6];
  float* out = (float*)d_out;

  const long D  = 1024;
  const long L  = 2048;
  const long ND = 8192 * D;
  const long NS = 4L * L * L;

  char* ws = (char*)d_ws;
  unsigned short* qh    = (unsigned short*)ws;         // 16 MB (z=0)
  unsigned short* kh    = qh  + ND;                    // 16 MB (z=1)
  unsigned short* vhT   = kh  + ND;                    // 16 MB (z=2, transposed)
  unsigned short* wbf   = vhT + ND;                    // 8 MB (4 weights)
  unsigned short* S     = wbf + 4L * D * D;            // 32 MB (bf16)
  unsigned short* qkvbf = S   + NS;                    // 48 MB (dead after proj)
  unsigned short* P     = qkvbf;                       // 32 MB, aliases dead qkv
  unsigned short* ybf   = P + NS;                      // 16 MB, aliases dead qkv

  // 1) convert inputs + weights to bf16
  convert_all<<<1792, 256, 0, stream>>>(q, k, v, Wq, Wk, Wv, Wp, qkvbf, wbf);

  // 2) merged projections, 2-phase 128^2 (z=3): qh, kh (bf16) and vhT
  gemm_bt<<<dim3(512, 3), 256, 0, stream>>>(qkvbf, wbf, qh,
      8192, 1024, 1024, 8, ND, D * D, ND, 3, 0, 1.0f);

  // 3) S = qh * kh^T * 0.125 (bf16 out), 8-phase 256^2, triangular 36 tiles/z
  gemm8p<<<dim3(36, 4), 512, 0, stream>>>(qh, kh, S,
      2048, 2048, 1024, 8, L * D, L * D, L * L, 0, 1, 0.125f);

  // 4) causal softmax (bf16 in/out, paired rows q & 2047-q)
  softmax_causal<<<4096, 256, 0, stream>>>(S, P);

  // 5) Y = P * vh — flat co-residency map (tilemap 3): twin blocks share mt
  gemm_bt<<<dim3(512, 1), 256, 0, stream>>>(P, vhT, ybf,
      2048, 1024, 2048, 8, L * L, D * L, L * D, 0, 3, 1.0f);

  // 6) out = Y * Wproj^T (fp32, 2-phase 128^2, 512 blocks)
  gemm_bt<<<dim3(512, 1), 256, 0, stream>>>(ybf, wbf + 3 * D * D, out,
      8192, 1024, 1024, 8, 0, 0, 0, 2, 0, 1.0f);
}

// Round 19
// 210.626 us; speedup vs baseline: 1.0465x; 1.0098x over previous
//
#include <hip/hip_runtime.h>
#include <hip/hip_bf16.h>
#include <stdint.h>

typedef __bf16 bf16x8 __attribute__((ext_vector_type(8)));
typedef float  f32x4  __attribute__((ext_vector_type(4)));
typedef unsigned short ushort8v __attribute__((ext_vector_type(8)));

__device__ __forceinline__ unsigned short f2bf(float f) {
  unsigned int u = __float_as_uint(f);
  u += 0x7FFF + ((u >> 16) & 1);          // round-to-nearest-even
  return (unsigned short)(u >> 16);
}
__device__ __forceinline__ float bf2f(unsigned short h) {
  return __uint_as_float(((unsigned int)h) << 16);
}

#define GLOAD_LDS(gptr, ldsptr)                                                     \
  __builtin_amdgcn_global_load_lds(                                                 \
      (const __attribute__((address_space(1))) unsigned int*)(gptr),                \
      (__attribute__((address_space(3))) unsigned int*)(ldsptr), 16, 0, 0)

// =============== 8-phase 256x256 GEMM (S-GEMM only: 144-block single round) ===============
// R12 schedule: staging to buf c^1 only, 1 half-tile lookahead, counted vmcnt(4),
// lgkmcnt(0)+sched_barrier after each barrier (rule 18). tilemap 1: triangular (nt<=mt).
__global__ __launch_bounds__(512, 1) void gemm8p(
    const unsigned short* __restrict__ A,
    const unsigned short* __restrict__ B,
    void* __restrict__ C,
    int M, int N, int K, int ntn,
    long sAz, long sBz, long sCz,
    int mode, int tilemap, float scale)
{
  int mt, nt;
  const int orig = blockIdx.x;
  if (tilemap == 0) {
    const int nwg = gridDim.x;
    const int qq = nwg >> 3, rr = nwg & 7, xcd = orig & 7, oo = orig >> 3;
    const int wg = (xcd < rr ? xcd * (qq + 1) : rr * (qq + 1) + (xcd - rr) * qq) + oo;
    mt = wg / ntn; nt = wg % ntn;
  } else {
    mt = (int)((sqrtf(8.f * orig + 1.f) - 1.f) * 0.5f);
    int base = mt * (mt + 1) / 2;
    if (orig < base) { mt--; base = mt * (mt + 1) / 2; }
    else if (orig >= base + mt + 1) { mt++; base = mt * (mt + 1) / 2; }
    nt = orig - base;
  }
  const int z = blockIdx.y;
  A += sAz * (long)z;
  B += sBz * (long)z;

  __shared__ __align__(16) unsigned short lds[65536];   // 128 KB

  const int tid  = threadIdx.x;
  const int wave = tid >> 6;
  const int lane = tid & 63;
  const int wr = wave >> 2, wc = wave & 3;
  const int li = lane & 15;
  const int rslot = (((lane >> 4) ^ ((lane >> 1) & 3)) << 4);

  f32x4 acc[8][4];
#pragma unroll
  for (int i = 0; i < 8; ++i)
#pragma unroll
    for (int j = 0; j < 4; ++j) acc[i][j] = (f32x4){0.f, 0.f, 0.f, 0.f};

  const int nkt = K / 64;

  const int srow = tid >> 2;
  const long scol = (long)(((tid & 3) ^ ((tid >> 3) & 3)) << 3);
  const long aoff0 = (long)(mt * 256 + srow) * K + scol;
  const long aoff1 = (long)(mt * 256 + 128 + srow) * K + scol;
  const long boff0 = (long)(nt * 256 + srow) * K + scol;
  const long boff1 = (long)(nt * 256 + 128 + srow) * K + scol;
  const int stw = wave * 1024;

#define AB(c, kh) (((c) * 2 + (kh)) * 16384)
#define BB(c, kh) (65536 + ((c) * 2 + (kh)) * 16384)
#define STAGE_A(c, kh, jt) do { const long o_ = (long)(jt) * 64 + (kh) * 32;        \
    GLOAD_LDS(A + aoff0 + o_, (char*)lds + AB(c, kh) + stw);                        \
    GLOAD_LDS(A + aoff1 + o_, (char*)lds + AB(c, kh) + 8192 + stw); } while (0)
#define STAGE_B(c, kh, jt) do { const long o_ = (long)(jt) * 64 + (kh) * 32;        \
    GLOAD_LDS(B + boff0 + o_, (char*)lds + BB(c, kh) + stw);                        \
    GLOAD_LDS(B + boff1 + o_, (char*)lds + BB(c, kh) + 8192 + stw); } while (0)
#define RD_A(c, kk, ms, mf) \
  (*(const bf16x8*)((const char*)lds + AB(c, kk) + (wr * 128 + (ms) * 64 + (mf) * 16 + li) * 64 + rslot))
#define RD_B(c, kk, nf) \
  (*(const bf16x8*)((const char*)lds + BB(c, kk) + (wc * 64 + (nf) * 16 + li) * 64 + rslot))
#define MM(msb, bb) do {                                                            \
    _Pragma("unroll")                                                               \
    for (int mf_ = 0; mf_ < 4; ++mf_)                                               \
    _Pragma("unroll")                                                               \
      for (int nf_ = 0; nf_ < 4; ++nf_)                                             \
        acc[(msb) + mf_][nf_] = __builtin_amdgcn_mfma_f32_16x16x32_bf16(            \
            a[mf_], bb[nf_], acc[(msb) + mf_][nf_], 0, 0, 0); } while (0)
#define LGKM0_FENCE do {                                                            \
    asm volatile("s_waitcnt lgkmcnt(0)" ::: "memory");                              \
    __builtin_amdgcn_sched_barrier(0); } while (0)
#define BARRIER do { __builtin_amdgcn_s_barrier();                                  \
    asm volatile("" ::: "memory"); } while (0)

  STAGE_A(0, 0, 0); STAGE_B(0, 0, 0); STAGE_A(0, 1, 0); STAGE_B(0, 1, 0);
  asm volatile("s_waitcnt vmcnt(0)" ::: "memory");
  BARRIER;

  bf16x8 a[4], b0[4], b1[4];
  for (int j = 0; j < nkt; ++j) {
    const int c = j & 1;
    const bool s1 = (j + 1 < nkt);

#pragma unroll
    for (int nf = 0; nf < 4; ++nf) b0[nf] = RD_B(c, 0, nf);
#pragma unroll
    for (int mf = 0; mf < 4; ++mf) a[mf] = RD_A(c, 0, 0, mf);
    if (s1) STAGE_A(c ^ 1, 0, j + 1);
    BARRIER;
    LGKM0_FENCE;
    __builtin_amdgcn_s_setprio(1);
    MM(0, b0);
    __builtin_amdgcn_s_setprio(0);
    BARRIER;

#pragma unroll
    for (int mf = 0; mf < 4; ++mf) a[mf] = RD_A(c, 0, 1, mf);
    if (s1) STAGE_B(c ^ 1, 0, j + 1);
    BARRIER;
    LGKM0_FENCE;
    __builtin_amdgcn_s_setprio(1);
    MM(4, b0);
    __builtin_amdgcn_s_setprio(0);
    if (s1) { asm volatile("s_waitcnt vmcnt(4)" ::: "memory"); }
    else    { asm volatile("s_waitcnt vmcnt(0)" ::: "memory"); }
    BARRIER;

#pragma unroll
    for (int nf = 0; nf < 4; ++nf) b1[nf] = RD_B(c, 1, nf);
#pragma unroll
    for (int mf = 0; mf < 4; ++mf) a[mf] = RD_A(c, 1, 0, mf);
    if (s1) STAGE_A(c ^ 1, 1, j + 1);
    BARRIER;
    LGKM0_FENCE;
    __builtin_amdgcn_s_setprio(1);
    MM(0, b1);
    __builtin_amdgcn_s_setprio(0);
    BARRIER;

#pragma unroll
    for (int mf = 0; mf < 4; ++mf) a[mf] = RD_A(c, 1, 1, mf);
    if (s1) STAGE_B(c ^ 1, 1, j + 1);
    BARRIER;
    LGKM0_FENCE;
    __builtin_amdgcn_s_setprio(1);
    MM(4, b1);
    __builtin_amdgcn_s_setprio(0);
    if (s1) { asm volatile("s_waitcnt vmcnt(4)" ::: "memory"); }
    BARRIER;
  }
#undef AB
#undef BB
#undef STAGE_A
#undef STAGE_B
#undef RD_A
#undef RD_B
#undef MM
#undef LGKM0_FENCE
#undef BARRIER

  const int rb = mt * 256 + wr * 128;
  const int cb = nt * 256 + wc * 64;
  unsigned short* Cb = (unsigned short*)C + sCz * (long)z;
#pragma unroll
  for (int mi = 0; mi < 8; ++mi)
#pragma unroll
    for (int ni = 0; ni < 4; ++ni) {
      const int row0 = rb + mi * 16 + ((lane >> 4) << 2);
      const int col  = cb + ni * 16 + (lane & 15);
#pragma unroll
      for (int jj = 0; jj < 4; ++jj)
        Cb[(long)(row0 + jj) * N + col] = f2bf(acc[mi][ni][jj] * scale);
    }
}

#define BM 128
#define BN 128
#define BK 32

// ============ 128x128 3-buf GEMM (proj / PV / out-proj) ============
// mode 0: C bf16 [M,N]*scale; mode 2: C fp32 [M,N]*scale
// mode 3: merged projections (z<2 -> bf16 [M,N]; z==2 -> vhT per-batch)
// tilemap 0: m204 XCD chunk swizzle; 2: paired causal map + K-limit (PV)
__global__ __launch_bounds__(256, 3) void gemm_bt(
    const unsigned short* __restrict__ A,
    const unsigned short* __restrict__ B,
    void* __restrict__ C,
    int M, int N, int K, int ntiles,
    long sAz, long sBz, long sCz,
    int mode, int tilemap, float scale)
{
  int mt, nt;
  const int orig = blockIdx.x;
  if (tilemap == 0) {
    const int nwg = gridDim.x;
    const int qq = nwg >> 3, rr = nwg & 7, xc = orig & 7, oo = orig >> 3;
    const int wg = (xc < rr ? xc * (qq + 1) : rr * (qq + 1) + (xc - rr) * qq) + oo;
    mt = wg / ntiles; nt = wg % ntiles;
  } else {
    const int c = orig & 15;
    mt = (c & 8) ? (15 - (c & 7)) : c;
    nt = orig >> 4;
  }
  const int z = blockIdx.y;
  const int emode = (mode == 3) ? (z == 2 ? 1 : 0) : mode;

  A += sAz * (long)z;
  B += sBz * (long)z;

  __shared__ __align__(16) unsigned short As[3][BM * BK];
  __shared__ __align__(16) unsigned short Bs[3][BN * BK];

  const int tid  = threadIdx.x;
  const int wave = tid >> 6;
  const int lane = tid & 63;
  const int wr = wave >> 1, wc = wave & 1;

  f32x4 acc[4][4];
#pragma unroll
  for (int i = 0; i < 4; ++i)
#pragma unroll
    for (int j = 0; j < 4; ++j) acc[i][j] = (f32x4){0.f, 0.f, 0.f, 0.f};

  int kiters = K / BK;
  if (tilemap == 2) { const int kl = (mt + 1) * (BM / BK); if (kl < kiters) kiters = kl; }

  const int r0 = tid >> 2, s0 = tid & 3;
  const int c0 = ((s0 ^ ((r0 >> 1) & 3)) << 3);
  const int r1 = r0 + 64;
  const int c1 = ((s0 ^ ((r1 >> 1) & 3)) << 3);
  const long aoff0 = (long)(mt * BM + r0) * K + c0;
  const long aoff1 = (long)(mt * BM + r1) * K + c1;
  const long boff0 = (long)(nt * BN + r0) * K + c0;
  const long boff1 = (long)(nt * BN + r1) * K + c1;
  const unsigned ldsw = wave * 1024;

#define STAGE(bi, k0)                                                     \
  do {                                                                    \
    GLOAD_LDS(A + aoff0 + (k0), (char*)&As[bi][0]    + ldsw);             \
    GLOAD_LDS(A + aoff1 + (k0), (char*)&As[bi][2048] + ldsw);             \
    GLOAD_LDS(B + boff0 + (k0), (char*)&Bs[bi][0]    + ldsw);             \
    GLOAD_LDS(B + boff1 + (k0), (char*)&Bs[bi][2048] + ldsw);             \
  } while (0)

  STAGE(0, 0);
  if (kiters > 1) STAGE(1, BK);

  int cur = 0;
  for (int kt = 0; kt < kiters; ++kt) {
    const int rem = kiters - 1 - kt;
    if (rem >= 2) {
      int sb = cur + 2; if (sb >= 3) sb -= 3;
      STAGE(sb, (kt + 2) * BK);
      asm volatile("s_waitcnt vmcnt(8)" ::: "memory");
    } else if (rem == 1) {
      asm volatile("s_waitcnt vmcnt(4)" ::: "memory");
    } else {
      asm volatile("s_waitcnt vmcnt(0)" ::: "memory");
    }
    __builtin_amdgcn_s_barrier();
    asm volatile("" ::: "memory");

    bf16x8 af[4], bfr[4];
#pragma unroll
    for (int i = 0; i < 4; ++i) {
      const int ar = wr * 64 + i * 16 + (lane & 15);
      const int as = ((lane >> 4) ^ ((ar >> 1) & 3)) << 3;
      af[i] = *(const bf16x8*)&As[cur][ar * BK + as];
      const int br = wc * 64 + i * 16 + (lane & 15);
      const int bs = ((lane >> 4) ^ ((br >> 1) & 3)) << 3;
      bfr[i] = *(const bf16x8*)&Bs[cur][br * BK + bs];
    }
#pragma unroll
    for (int mi = 0; mi < 4; ++mi)
#pragma unroll
      for (int ni = 0; ni < 4; ++ni)
        acc[mi][ni] = __builtin_amdgcn_mfma_f32_16x16x32_bf16(af[mi], bfr[ni], acc[mi][ni], 0, 0, 0);

    asm volatile("" ::: "memory");
    __builtin_amdgcn_s_barrier();
    cur = (cur == 2) ? 0 : cur + 1;
  }
#undef STAGE

  const int rb = mt * BM + wr * 64;
  const int cb = nt * BN + wc * 64;

  if (emode == 0) {
    unsigned short* Cb = (unsigned short*)C + sCz * (long)z;
#pragma unroll
    for (int mi = 0; mi < 4; ++mi)
#pragma unroll
      for (int ni = 0; ni < 4; ++ni) {
        const int row0 = rb + mi * 16 + ((lane >> 4) << 2);
        const int col  = cb + ni * 16 + (lane & 15);
#pragma unroll
        for (int j = 0; j < 4; ++j)
          Cb[(long)(row0 + j) * N + col] = f2bf(acc[mi][ni][j] * scale);
      }
  } else if (emode == 1) {
    unsigned short* Cb = (unsigned short*)C + sCz * (long)z;
#pragma unroll
    for (int mi = 0; mi < 4; ++mi)
#pragma unroll
      for (int ni = 0; ni < 4; ++ni) {
        const int row0 = rb + mi * 16 + ((lane >> 4) << 2);
        const int col  = cb + ni * 16 + (lane & 15);
#pragma unroll
        for (int j = 0; j < 4; ++j) {
          const int row = row0 + j;
          const int b = row >> 11, l = row & 2047;
          Cb[((long)b * N + col) * 2048 + l] = f2bf(acc[mi][ni][j]);
        }
      }
  } else {
    float* Cf = (float*)C + sCz * (long)z;
#pragma unroll
    for (int mi = 0; mi < 4; ++mi)
#pragma unroll
      for (int ni = 0; ni < 4; ++ni) {
        const int row0 = rb + mi * 16 + ((lane >> 4) << 2);
        const int col  = cb + ni * 16 + (lane & 15);
#pragma unroll
        for (int j = 0; j < 4; ++j)
          Cf[(long)(row0 + j) * N + col] = acc[mi][ni][j] * scale;
      }
  }
}

// work-balanced paired causal softmax: block handles rows q and 2047-q of one batch.
__global__ __launch_bounds__(256) void softmax_causal(
    const unsigned short* __restrict__ S, unsigned short* __restrict__ P)
{
  const int pid = blockIdx.x;            // 0..4095
  const int b = pid >> 10;
  const int qa = pid & 1023;
  const int tid = threadIdx.x, lane = tid & 63, wave = tid >> 6;
  const int base = tid * 8;
  __shared__ float red[8];

#pragma unroll
  for (int half = 0; half < 2; ++half) {
    const int q = half ? (2047 - qa) : qa;
    const unsigned short* srow = S + ((long)b * 2048 + q) * 2048;
    unsigned short* prow = P + ((long)b * 2048 + q) * 2048;
    const int len = q + 1;
    const int lenceil = ((q >> 7) + 1) << 7;
    const bool active = base < lenceil;

    float vv[8];
#pragma unroll
    for (int i = 0; i < 8; ++i) vv[i] = -3.4e38f;
    if (active) {
      ushort8v xv = *(const ushort8v*)(srow + base);
#pragma unroll
      for (int i = 0; i < 8; ++i) vv[i] = bf2f(xv[i]);
    }

    float m = -3.4e38f;
#pragma unroll
    for (int i = 0; i < 8; ++i) if (base + i < len) m = fmaxf(m, vv[i]);
#pragma unroll
    for (int o = 32; o; o >>= 1) m = fmaxf(m, __shfl_xor(m, o));
    if (lane == 0) red[wave] = m;
    __syncthreads();
    m = fmaxf(fmaxf(red[0], red[1]), fmaxf(red[2], red[3]));

    float p[8], s = 0.f;
#pragma unroll
    for (int i = 0; i < 8; ++i) {
      p[i] = (base + i < len) ? __expf(vv[i] - m) : 0.f;
      s += p[i];
    }
#pragma unroll
    for (int o = 32; o; o >>= 1) s += __shfl_xor(s, o);
    if (lane == 0) red[4 + wave] = s;
    __syncthreads();
    s = (red[4] + red[5]) + (red[6] + red[7]);
    const float inv = 1.f / s;

    if (active) {
      ushort8v o16;
#pragma unroll
      for (int i = 0; i < 8; ++i) o16[i] = f2bf(p[i] * inv);
      *(ushort8v*)(prow + base) = o16;
    }
    __syncthreads();
  }
}

// merged fp32 -> bf16 (RNE): q,k,v + 4 weights
__global__ __launch_bounds__(256) void convert_all(
    const float* __restrict__ q, const float* __restrict__ k, const float* __restrict__ v,
    const float* __restrict__ wq, const float* __restrict__ wk,
    const float* __restrict__ wv, const float* __restrict__ wp,
    unsigned short* __restrict__ qkv, unsigned short* __restrict__ wb)
{
  const long NQ = 8192L * 1024 / 4;
  const long NW = 1024L * 1024 / 4;
  const int blk = blockIdx.x;
  const float* src; unsigned short* dst; long n; int nb, bb;
  if (blk < 1536) {
    const int s = blk >> 9;
    src = (s == 0) ? q : (s == 1) ? k : v;
    dst = qkv + (long)s * (8192L * 1024);
    n = NQ; nb = 512; bb = blk & 511;
  } else {
    const int s = (blk - 1536) >> 6;
    src = (s == 0) ? wq : (s == 1) ? wk : (s == 2) ? wv : wp;
    dst = wb + (long)s * (1024L * 1024);
    n = NW; nb = 64; bb = (blk - 1536) & 63;
  }
  for (long i = (long)bb * 256 + threadIdx.x; i < n; i += (long)nb * 256) {
    float4 x = ((const float4*)src)[i];
    ushort4 o;
    o.x = f2bf(x.x); o.y = f2bf(x.y); o.z = f2bf(x.z); o.w = f2bf(x.w);
    ((ushort4*)dst)[i] = o;
  }
}

extern "C" void kernel_launch(void* const* d_in, const int* in_sizes, int n_in,
                              void* d_out, int out_size, void* d_ws, size_t ws_size,
                              hipStream_t stream) {
  const float* q  = (const float*)d_in[0];
  const float* k  = (const float*)d_in[1];
  const float* v  = (const float*)d_in[2];
  const float* Wq = (const float*)d_in[3];
  const float* Wk = (const float*)d_in[4];
  const float* Wv = (const float*)d_in[5];
  const float* Wp = (const float*)d_in[6];
  float* out = (float*)d_out;

  const long D  = 1024;
  const long L  = 2048;
  const long ND = 8192 * D;
  const long NS = 4L * L * L;

  char* ws = (char*)d_ws;
  unsigned short* qh    = (unsigned short*)ws;         // 16 MB (z=0)
  unsigned short* kh    = qh  + ND;                    // 16 MB (z=1)
  unsigned short* vhT   = kh  + ND;                    // 16 MB (z=2, transposed)
  unsigned short* wbf   = vhT + ND;                    // 8 MB (4 weights)
  unsigned short* S     = wbf + 4L * D * D;            // 32 MB (bf16)
  unsigned short* qkvbf = S   + NS;                    // 48 MB (dead after proj)
  unsigned short* P     = qkvbf;                       // 32 MB, aliases dead qkv
  unsigned short* ybf   = P + NS;                      // 16 MB, aliases dead qkv

  // 1) convert inputs + weights to bf16
  convert_all<<<1792, 256, 0, stream>>>(q, k, v, Wq, Wk, Wv, Wp, qkvbf, wbf);

  // 2) merged projections, 2-phase 128^2 (z=3): qh, kh (bf16) and vhT
  gemm_bt<<<dim3(512, 3), 256, 0, stream>>>(qkvbf, wbf, qh,
      8192, 1024, 1024, 8, ND, D * D, ND, 3, 0, 1.0f);

  // 3) S = qh * kh^T * 0.125 (bf16 out), 8-phase 256^2, triangular 36 tiles/z
  gemm8p<<<dim3(36, 4), 512, 0, stream>>>(qh, kh, S,
      2048, 2048, 1024, 8, L * D, L * D, L * L, 0, 1, 0.125f);

  // 4) causal softmax (bf16 in/out, paired rows q & 2047-q)
  softmax_causal<<<4096, 256, 0, stream>>>(S, P);

  // 5) Y = P * vh (paired XCD map + K-limit)
  gemm_bt<<<dim3(128, 4), 256, 0, stream>>>(P, vhT, ybf,
      2048, 1024, 2048, 8, L * L, D * L, L * D, 0, 2, 1.0f);

  // 6) out = Y * Wproj^T (fp32, 2-phase 128^2, 512 blocks)
  gemm_bt<<<dim3(512, 1), 256, 0, stream>>>(ybf, wbf + 3 * D * D, out,
      8192, 1024, 1024, 8, 0, 0, 0, 2, 0, 1.0f);
}